// Round 4
// baseline (1275.286 us; speedup 1.0000x reference)
//
#include <hip/hip_runtime.h>
#include <math.h>

static constexpr int N_NODES = 50000;
static constexpr int N_EDGES = 800000;
static constexpr int DMODEL  = 128;
static constexpr int MTILES  = N_NODES / 16;   // 3125 exactly

typedef __attribute__((ext_vector_type(8))) short short8;   // 8 bf16 (4 VGPRs)
typedef __attribute__((ext_vector_type(4))) float float4v;  // 4 fp32 acc

__device__ __forceinline__ unsigned short f2bf(float f) {
    unsigned u = __builtin_bit_cast(unsigned, f);
    u += 0x7fffu + ((u >> 16) & 1u);
    return (unsigned short)(u >> 16);
}
__device__ __forceinline__ float bf2f(unsigned short b) {
    unsigned u = ((unsigned)b) << 16;
    return __builtin_bit_cast(float, u);
}
__device__ __forceinline__ float bflo(unsigned w) {   // low bf16 -> f32 (1 shl)
    return __builtin_bit_cast(float, w << 16);
}
__device__ __forceinline__ float bfhi(unsigned w) {   // high bf16 -> f32 (1 and)
    return __builtin_bit_cast(float, w & 0xffff0000u);
}

// ---------------------------------------------------------------------------
// Weight prep: fp32 [K][N] row-major -> bf16 MFMA B-fragment order.
//   idx = (nt*ksteps + s)*512 + quad*128 + c*8 + j   (nt=n>>4, c=n&15, s=k>>5)
// ---------------------------------------------------------------------------
struct PrepSeg { const float* src; int K; int N; int dstOff; };
struct PrepArgs { PrepSeg seg[13]; };

__global__ void prep_kernel(PrepArgs pa, unsigned short* wf)
{
    PrepSeg sg = pa.seg[blockIdx.y];
    int e = blockIdx.x * 256 + threadIdx.x;
    int total = sg.K * sg.N;
    if (e >= total) return;
    int n = e % sg.N;
    int k = e / sg.N;
    int ks = sg.K >> 5;
    int nt = n >> 4, c = n & 15, s = k >> 5, q = (k >> 3) & 3, jj = k & 7;
    int di = sg.dstOff + (nt * ks + s) * 512 + q * 128 + c * 8 + jj;
    wf[di] = f2bf(sg.src[e]);
}

// ---------------------------------------------------------------------------
// LDS-free MFMA GEMM body, persistent waves + atomic tile queue.
// B-frags resident in VGPRs (loaded once per wave). EPI: 0=bias, 1=bias+relu,
// 2=bias+residual, 3=bias+residual+LayerNorm (needs NT*16==128, colBase==0).
// ---------------------------------------------------------------------------
template<int KSTEPS, int NT, int EPI, bool AF32, bool WRF, bool WRB>
__device__ __forceinline__ void gemm_body(
    const void* __restrict__ Ap, const unsigned short* __restrict__ Wfc,
    const float* __restrict__ bias, const float* res,
    float* Cf, unsigned short* Cb,
    const float* __restrict__ lnw, const float* __restrict__ lnb,
    int ldA, int ldC, int mtiles, int colBase, int* tileCnt)
{
    const int lane = threadIdx.x & 63;
    const int c = lane & 15;
    const int q = lane >> 4;

    short8 bfrag[NT][KSTEPS];
#pragma unroll
    for (int nt = 0; nt < NT; ++nt)
#pragma unroll
        for (int s = 0; s < KSTEPS; ++s)
            bfrag[nt][s] = *(const short8*)(Wfc + (nt * KSTEPS + s) * 512 + lane * 8);

    float bb[NT];
#pragma unroll
    for (int nt = 0; nt < NT; ++nt)
        bb[nt] = bias ? bias[colBase + nt * 16 + c] : 0.f;

    float lw[NT], lb[NT];
    if (EPI == 3) {
#pragma unroll
        for (int nt = 0; nt < NT; ++nt) {
            lw[nt] = lnw[nt * 16 + c];
            lb[nt] = lnb[nt * 16 + c];
        }
    }

    for (;;) {
        int mt;
        if (lane == 0) mt = atomicAdd(tileCnt, 1);
        mt = __shfl(mt, 0, 64);
        if (mt >= mtiles) break;

        const int row0 = mt * 16;
        short8 afrag[KSTEPS];
        if (AF32) {
            const float* A32 = (const float*)Ap;
#pragma unroll
            for (int s = 0; s < KSTEPS; ++s) {
                const float4* p = (const float4*)(A32 + (size_t)(row0 + c) * ldA + s * 32 + q * 8);
                float4 x0 = p[0], x1 = p[1];
                short8 a;
                a[0] = (short)f2bf(x0.x); a[1] = (short)f2bf(x0.y);
                a[2] = (short)f2bf(x0.z); a[3] = (short)f2bf(x0.w);
                a[4] = (short)f2bf(x1.x); a[5] = (short)f2bf(x1.y);
                a[6] = (short)f2bf(x1.z); a[7] = (short)f2bf(x1.w);
                afrag[s] = a;
            }
        } else {
            const unsigned short* Ab = (const unsigned short*)Ap;
#pragma unroll
            for (int s = 0; s < KSTEPS; ++s)
                afrag[s] = *(const short8*)(Ab + (size_t)(row0 + c) * ldA + s * 32 + q * 8);
        }

        float4v acc[NT];
#pragma unroll
        for (int nt = 0; nt < NT; ++nt) acc[nt] = (float4v)0.f;
#pragma unroll
        for (int s = 0; s < KSTEPS; ++s)
#pragma unroll
            for (int nt = 0; nt < NT; ++nt)
                acc[nt] = __builtin_amdgcn_mfma_f32_16x16x32_bf16(afrag[s], bfrag[nt][s], acc[nt], 0, 0, 0);

        // epilogue: C row = row0 + q*4 + r, col = colBase + nt*16 + c
#pragma unroll
        for (int nt = 0; nt < NT; ++nt) {
            const int col = colBase + nt * 16 + c;
#pragma unroll
            for (int r = 0; r < 4; ++r) {
                const int grow = row0 + q * 4 + r;
                float v = acc[nt][r] + bb[nt];
                if (EPI == 2 || EPI == 3) v += res[(size_t)grow * ldC + col];
                if (EPI == 1) v = fmaxf(v, 0.f);
                acc[nt][r] = v;
            }
        }

        if (EPI == 3) {
#pragma unroll
            for (int r = 0; r < 4; ++r) {
                float s = 0.f, ss = 0.f;
#pragma unroll
                for (int nt = 0; nt < NT; ++nt) {
                    float v = acc[nt][r];
                    s += v; ss = fmaf(v, v, ss);
                }
#pragma unroll
                for (int o = 1; o < 16; o <<= 1) {
                    s  += __shfl_xor(s, o, 64);
                    ss += __shfl_xor(ss, o, 64);
                }
                float m   = s * (1.0f / 128.0f);
                float var = ss * (1.0f / 128.0f) - m * m;
                float rs  = rsqrtf(var + 1e-5f);
                const int grow = row0 + q * 4 + r;
#pragma unroll
                for (int nt = 0; nt < NT; ++nt) {
                    float v = (acc[nt][r] - m) * rs * lw[nt] + lb[nt];
                    if (WRF) Cf[(size_t)grow * ldC + nt * 16 + c] = v;
                    if (WRB) Cb[(size_t)grow * ldC + nt * 16 + c] = f2bf(v);
                }
            }
        } else {
#pragma unroll
            for (int nt = 0; nt < NT; ++nt) {
                const int col = colBase + nt * 16 + c;
#pragma unroll
                for (int r = 0; r < 4; ++r) {
                    const int grow = row0 + q * 4 + r;
                    if (WRF) Cf[(size_t)grow * ldC + col] = acc[nt][r];
                    if (WRB) Cb[(size_t)grow * ldC + col] = f2bf(acc[nt][r]);
                }
            }
        }
    }
}

template<int KSTEPS, int NT, int EPI, bool AF32, bool WRF, bool WRB>
__global__ __launch_bounds__(256, 2)
void mfma_gemm(const void* __restrict__ Ap, const unsigned short* __restrict__ Wf,
               const float* __restrict__ bias, const float* res,
               float* Cf, unsigned short* Cb,
               const float* __restrict__ lnw, const float* __restrict__ lnb,
               int ldA, int ldC, int mtiles, int* tileCnt)
{
    const int colBase = blockIdx.y * NT * 16;
    const unsigned short* Wfc = Wf + (size_t)blockIdx.y * NT * KSTEPS * 512;
    gemm_body<KSTEPS, NT, EPI, AF32, WRF, WRB>(
        Ap, Wfc, bias, res, Cf, Cb, lnw, lnb, ldA, ldC, mtiles, colBase,
        tileCnt + blockIdx.y);
}

// Q/K/V fused: blockIdx.y in {0,1,2} selects weight block, bias, output.
struct QkvPtrs { const float* bias[3]; unsigned short* out[3]; };

__global__ __launch_bounds__(256, 2)
void qkv_gemm(const unsigned short* __restrict__ A, const unsigned short* __restrict__ WfBase,
              QkvPtrs ptrs, int mtiles, int* tileCnt)
{
    const int sel = blockIdx.y;
    gemm_body<4, 8, 0, false, false, true>(
        A, WfBase + (size_t)sel * 32768, ptrs.bias[sel], nullptr,
        nullptr, ptrs.out[sel], nullptr, nullptr, 128, 128, mtiles, 0,
        tileCnt + sel);
}

// ---------------------------------------------------------------------------
// FFN2 + residual + LN2 fused. K=256 (KSTEPS=8), NT=8 -> full 128-col rows.
// B-frags streamed per k-step from L2 (would need 256 VGPRs resident).
// res aliases outF for layer 0 (row owned by one wave: read-then-write, ok).
// ---------------------------------------------------------------------------
__global__ __launch_bounds__(256, 2)
void ffn2_ln_gemm(const unsigned short* __restrict__ A, const unsigned short* __restrict__ Wf,
                  const float* __restrict__ bias, const float* res,
                  float* outF, unsigned short* outB,
                  const float* __restrict__ lnw, const float* __restrict__ lnb,
                  int mtiles, int* tileCnt)
{
    const int lane = threadIdx.x & 63;
    const int c = lane & 15;
    const int q = lane >> 4;

    float bb[8], lw[8], lb[8];
#pragma unroll
    for (int nt = 0; nt < 8; ++nt) {
        bb[nt] = bias[nt * 16 + c];
        lw[nt] = lnw[nt * 16 + c];
        lb[nt] = lnb[nt * 16 + c];
    }

    for (;;) {
        int mt;
        if (lane == 0) mt = atomicAdd(tileCnt, 1);
        mt = __shfl(mt, 0, 64);
        if (mt >= mtiles) break;

        const int row0 = mt * 16;
        short8 afrag[8];
#pragma unroll
        for (int s = 0; s < 8; ++s)
            afrag[s] = *(const short8*)(A + (size_t)(row0 + c) * 256 + s * 32 + q * 8);

        float4v acc[8];
#pragma unroll
        for (int nt = 0; nt < 8; ++nt) acc[nt] = (float4v)0.f;

#pragma unroll
        for (int s = 0; s < 8; ++s) {
            short8 bfr[8];
#pragma unroll
            for (int nt = 0; nt < 8; ++nt)
                bfr[nt] = *(const short8*)(Wf + (size_t)(nt * 8 + s) * 512 + lane * 8);
#pragma unroll
            for (int nt = 0; nt < 8; ++nt)
                acc[nt] = __builtin_amdgcn_mfma_f32_16x16x32_bf16(afrag[s], bfr[nt], acc[nt], 0, 0, 0);
        }

        // bias + residual
#pragma unroll
        for (int nt = 0; nt < 8; ++nt)
#pragma unroll
            for (int r = 0; r < 4; ++r) {
                const int grow = row0 + q * 4 + r;
                acc[nt][r] += bb[nt] + res[(size_t)grow * 128 + nt * 16 + c];
            }

        // row LayerNorm + store
#pragma unroll
        for (int r = 0; r < 4; ++r) {
            float s = 0.f, ss = 0.f;
#pragma unroll
            for (int nt = 0; nt < 8; ++nt) {
                float v = acc[nt][r];
                s += v; ss = fmaf(v, v, ss);
            }
#pragma unroll
            for (int o = 1; o < 16; o <<= 1) {
                s  += __shfl_xor(s, o, 64);
                ss += __shfl_xor(ss, o, 64);
            }
            float m   = s * (1.0f / 128.0f);
            float var = ss * (1.0f / 128.0f) - m * m;
            float rs  = rsqrtf(var + 1e-5f);
            const int grow = row0 + q * 4 + r;
#pragma unroll
            for (int nt = 0; nt < 8; ++nt) {
                float v = (acc[nt][r] - m) * rs * lw[nt] + lb[nt];
                outF[(size_t)grow * 128 + nt * 16 + c] = v;
                if (outB) outB[(size_t)grow * 128 + nt * 16 + c] = f2bf(v);
            }
        }
    }
}

// ---------------------------------------------------------------------------
// CSR build: histogram -> scan -> scatter (offsets become segment ends).
// ---------------------------------------------------------------------------
__global__ void hist_kernel(const int* __restrict__ dst, int* counts, int E)
{
    int e = blockIdx.x * 256 + threadIdx.x;
    if (e < E) atomicAdd(&counts[dst[e]], 1);
}

__global__ __launch_bounds__(1024)
void scan1_kernel(const int* __restrict__ counts, int* offsets, int* blockSums, int N)
{
    __shared__ int sm[1024];
    int t = threadIdx.x;
    int i = blockIdx.x * 1024 + t;
    sm[t] = (i < N) ? counts[i] : 0;
    __syncthreads();
#pragma unroll
    for (int o = 1; o < 1024; o <<= 1) {
        int v = (t >= o) ? sm[t - o] : 0;
        __syncthreads();
        sm[t] += v;
        __syncthreads();
    }
    if (i < N) offsets[i + 1] = sm[t];
    if (t == 1023) blockSums[blockIdx.x] = sm[t];
}

__global__ void scan2_kernel(int* blockSums, int nb)
{
    int t = threadIdx.x;
    int own = (t < nb) ? blockSums[t] : 0;
    int x = own;
#pragma unroll
    for (int o = 1; o < 64; o <<= 1) {
        int v = __shfl_up(x, o, 64);
        if (t >= o) x += v;
    }
    if (t < nb) blockSums[t] = x - own;
}

__global__ __launch_bounds__(1024)
void scan3_kernel(int* offsets, const int* __restrict__ blockSums, int N)
{
    int i = blockIdx.x * 1024 + threadIdx.x;
    if (i < N) offsets[i + 1] += blockSums[blockIdx.x];
    if (i == 0) offsets[0] = 0;
}

__global__ void scatter_kernel(const int* __restrict__ src, const int* __restrict__ dst,
                               int* offsets, int* esrc, int E)
{
    int e = blockIdx.x * 256 + threadIdx.x;
    if (e < E) {
        int d = dst[e];
        int pos = atomicAdd(&offsets[d], 1);
        esrc[pos] = src[e];
    }
}

// ---------------------------------------------------------------------------
// Attention aggregation, 4x unrolled. 32-bit byte offsets off uniform bases
// (saddr-friendly), med3 clamp, single exp2. One wave per dst node.
// attn may alias q (row n read+written only by wave n).
// ---------------------------------------------------------------------------
__global__ __launch_bounds__(256)
void agg_kernel(const unsigned short* qv, const unsigned short* __restrict__ kv,
                const unsigned short* __restrict__ vv, const int* __restrict__ offsets,
                const int* __restrict__ esrc, unsigned short* attn, int n_nodes)
{
    int w    = (int)((blockIdx.x * 256 + threadIdx.x) >> 6);
    int lane = threadIdx.x & 63;
    if (w >= n_nodes) return;
    const unsigned lane4 = (unsigned)lane * 4u;
    const char* kvc = (const char*)kv;
    const char* vvc = (const char*)vv;

    unsigned qb = *(const unsigned*)((const char*)qv + (((unsigned)w << 8) + lane4));
    float qx = bflo(qb), qy = bfhi(qb);
    int beg = (w == 0) ? 0 : offsets[w - 1];
    int end = offsets[w];
    float accx = 0.f, accy = 0.f, z = 0.f;
    const float SCL = 0.36067376022224085f;   // 0.25 * log2(e)

    for (int e = beg; e < end; e += 4) {
        int rem = end - e;
        unsigned o0 = ((unsigned)esrc[e] << 8) + lane4;
        unsigned o1 = ((unsigned)esrc[rem > 1 ? e + 1 : e] << 8) + lane4;
        unsigned o2 = ((unsigned)esrc[rem > 2 ? e + 2 : e] << 8) + lane4;
        unsigned o3 = ((unsigned)esrc[rem > 3 ? e + 3 : e] << 8) + lane4;
        unsigned kb0 = *(const unsigned*)(kvc + o0);
        unsigned kb1 = *(const unsigned*)(kvc + o1);
        unsigned kb2 = *(const unsigned*)(kvc + o2);
        unsigned kb3 = *(const unsigned*)(kvc + o3);
        unsigned vb0 = *(const unsigned*)(vvc + o0);
        unsigned vb1 = *(const unsigned*)(vvc + o1);
        unsigned vb2 = *(const unsigned*)(vvc + o2);
        unsigned vb3 = *(const unsigned*)(vvc + o3);

        float p0 = bflo(kb0) * qx + bfhi(kb0) * qy;
        float p1 = bflo(kb1) * qx + bfhi(kb1) * qy;
        float p2 = bflo(kb2) * qx + bfhi(kb2) * qy;
        float p3 = bflo(kb3) * qx + bfhi(kb3) * qy;
#pragma unroll
        for (int o = 1; o < 8; o <<= 1) {
            p0 += __shfl_xor(p0, o, 8);
            p1 += __shfl_xor(p1, o, 8);
            p2 += __shfl_xor(p2, o, 8);
            p3 += __shfl_xor(p3, o, 8);
        }
        float m1 = (rem > 1) ? 1.f : 0.f;
        float m2 = (rem > 2) ? 1.f : 0.f;
        float m3 = (rem > 3) ? 1.f : 0.f;
        // exp(clip(p*0.25,-5,5)) == exp2(med3(p,-20,20) * 0.25*log2e)
        float sv0 = exp2f(__builtin_amdgcn_fmed3f(p0, -20.f, 20.f) * SCL);
        float sv1 = exp2f(__builtin_amdgcn_fmed3f(p1, -20.f, 20.f) * SCL) * m1;
        float sv2 = exp2f(__builtin_amdgcn_fmed3f(p2, -20.f, 20.f) * SCL) * m2;
        float sv3 = exp2f(__builtin_amdgcn_fmed3f(p3, -20.f, 20.f) * SCL) * m3;

        accx = fmaf(sv0, bflo(vb0), accx);
        accy = fmaf(sv0, bfhi(vb0), accy);
        accx = fmaf(sv1, bflo(vb1), accx);
        accy = fmaf(sv1, bfhi(vb1), accy);
        accx = fmaf(sv2, bflo(vb2), accx);
        accy = fmaf(sv2, bfhi(vb2), accy);
        accx = fmaf(sv3, bflo(vb3), accx);
        accy = fmaf(sv3, bfhi(vb3), accy);
        z += sv0 + sv1 + sv2 + sv3;
    }
    float inv = 1.f / (z + 1e-6f);
    unsigned outw = (unsigned)f2bf(accx * inv) | ((unsigned)f2bf(accy * inv) << 16);
    *(unsigned*)((char*)attn + (((unsigned)w << 8) + lane4)) = outw;
}

// ---------------------------------------------------------------------------
extern "C" void kernel_launch(void* const* d_in, const int* in_sizes, int n_in,
                              void* d_out, int out_size, void* d_ws, size_t ws_size,
                              hipStream_t stream)
{
    const float* h_in  = (const float*)d_in[0];
    const int*   src   = (const int*)d_in[1];
    const int*   dst   = (const int*)d_in[2];
    const float* W_emb = (const float*)d_in[3];
    const float* Wq    = (const float*)d_in[4];
    const float* bq    = (const float*)d_in[5];
    const float* Wk    = (const float*)d_in[6];
    const float* bk    = (const float*)d_in[7];
    const float* Wv    = (const float*)d_in[8];
    const float* bv    = (const float*)d_in[9];
    const float* Wo    = (const float*)d_in[10];
    const float* bo    = (const float*)d_in[11];
    const float* ln1w  = (const float*)d_in[12];
    const float* ln1b  = (const float*)d_in[13];
    const float* Wf1   = (const float*)d_in[14];
    const float* bf1   = (const float*)d_in[15];
    const float* Wf2   = (const float*)d_in[16];
    const float* bf2   = (const float*)d_in[17];
    const float* ln2w  = (const float*)d_in[18];
    const float* ln2b  = (const float*)d_in[19];
    float* out = (float*)d_out;

    const int N = N_NODES, E = N_EDGES;
    const size_t NF = (size_t)N * DMODEL;

    float*          hbuf = (float*)d_ws;
    unsigned short* hbf  = (unsigned short*)(hbuf + NF);
    unsigned short* qbuf = hbf + NF;
    unsigned short* kbuf = qbuf + NF;
    unsigned short* vbuf = kbuf + NF;
    unsigned short* wf   = vbuf + NF;
    int* offsets   = (int*)(wf + 278528);
    int* blockSums = offsets + (N + 1);
    int* counts    = blockSums + 64;          // N ints
    int* tileCnt   = counts + N;              // 64 ints (zeroed with counts)
    int* esrc      = tileCnt + 64;            // E
    unsigned short* fbuf = kbuf;              // [N][256] bf16 FFN hidden

    const int EMB_O = 0, Q_O = 16384, K_O = 49152, V_O = 81920, O_O = 114688,
              F1_O = 147456, F2_O = 212992;

    const int edgeBlocks = (E + 255) / 256;
    const int scanBlocks = (N + 1023) / 1024;
    const int rowBlocks  = (N + 3) / 4;
    const int GX = 512;                       // 2 blocks/CU; atomic queue balances

    // ---- zero histogram + tile counters ----
    hipMemsetAsync(counts, 0, (size_t)(N + 64) * sizeof(int), stream);

    // ---- CSR build ----
    hist_kernel<<<edgeBlocks, 256, 0, stream>>>(dst, counts, E);
    scan1_kernel<<<scanBlocks, 1024, 0, stream>>>(counts, offsets, blockSums, N);
    scan2_kernel<<<1, 64, 0, stream>>>(blockSums, scanBlocks);
    scan3_kernel<<<scanBlocks, 1024, 0, stream>>>(offsets, blockSums, N);
    scatter_kernel<<<edgeBlocks, 256, 0, stream>>>(src, dst, offsets, esrc, E);

    // ---- weight prep ----
    PrepArgs pa;
    pa.seg[0]  = {W_emb,          128, 128, EMB_O};
    pa.seg[1]  = {Wq,             128, 128, Q_O};
    pa.seg[2]  = {Wq + 16384,     128, 128, Q_O + 16384};
    pa.seg[3]  = {Wk,             128, 128, K_O};
    pa.seg[4]  = {Wk + 16384,     128, 128, K_O + 16384};
    pa.seg[5]  = {Wv,             128, 128, V_O};
    pa.seg[6]  = {Wv + 16384,     128, 128, V_O + 16384};
    pa.seg[7]  = {Wo,             128, 128, O_O};
    pa.seg[8]  = {Wo + 16384,     128, 128, O_O + 16384};
    pa.seg[9]  = {Wf1,            128, 256, F1_O};
    pa.seg[10] = {Wf1 + 32768,    128, 256, F1_O + 32768};
    pa.seg[11] = {Wf2,            256, 128, F2_O};
    pa.seg[12] = {Wf2 + 32768,    256, 128, F2_O + 32768};
    prep_kernel<<<dim3(128, 13), 256, 0, stream>>>(pa, wf);

    // ---- embedding: h = h_in @ W_emb (fp32 A) -> hbuf + hbf ----
    mfma_gemm<4, 8, 0, true, true, true><<<dim3(GX, 1), 256, 0, stream>>>(
        h_in, wf + EMB_O, nullptr, nullptr, hbuf, hbf, nullptr, nullptr,
        128, 128, MTILES, tileCnt + 0);

    for (int l = 0; l < 2; ++l) {
        const int cbase = 4 + l * 16;
        // Q,K,V in one dispatch
        QkvPtrs qp;
        qp.bias[0] = bq + l * 128; qp.bias[1] = bk + l * 128; qp.bias[2] = bv + l * 128;
        qp.out[0] = qbuf; qp.out[1] = kbuf; qp.out[2] = vbuf;
        qkv_gemm<<<dim3(GX, 3), 256, 0, stream>>>(hbf, wf + Q_O + l * 16384, qp, MTILES,
                                                  tileCnt + cbase);

        // attention aggregate (attn aliases qbuf)
        agg_kernel<<<rowBlocks, 256, 0, stream>>>(qbuf, kbuf, vbuf, offsets, esrc, qbuf, N);

        // hx = LN1(h + attn @ Wo + bo) -> hbuf + hbf
        mfma_gemm<4, 8, 3, false, true, true><<<dim3(GX, 1), 256, 0, stream>>>(
            qbuf, wf + O_O + l * 16384, bo + l * 128, hbuf, hbuf, hbf,
            ln1w + l * 128, ln1b + l * 128, 128, 128, MTILES, tileCnt + cbase + 4);

        // f1 = relu(hx @ Wf1 + bf1) -> bf16 [N,256]
        mfma_gemm<4, 8, 1, false, false, true><<<dim3(GX, 2), 256, 0, stream>>>(
            hbf, wf + F1_O + l * 32768, bf1 + l * 256, nullptr, nullptr, fbuf,
            nullptr, nullptr, 128, 256, MTILES, tileCnt + cbase + 8);

        // h = LN2(hx + f1 @ Wf2 + bf2)  [fused] -> hbuf+hbf (l0) or out (l1)
        if (l == 0)
            ffn2_ln_gemm<<<dim3(GX, 1), 256, 0, stream>>>(
                fbuf, wf + F2_O, bf2, hbuf, hbuf, hbf, ln2w, ln2b,
                MTILES, tileCnt + cbase + 12);
        else
            ffn2_ln_gemm<<<dim3(GX, 1), 256, 0, stream>>>(
                fbuf, wf + F2_O + 32768, bf2 + 128, hbuf, out, nullptr,
                ln2w + 128, ln2b + 128, MTILES, tileCnt + cbase + 12);
    }
}

// Round 5
// 513.376 us; speedup vs baseline: 2.4841x; 2.4841x over previous
//
#include <hip/hip_runtime.h>
#include <math.h>

static constexpr int N_NODES = 50000;
static constexpr int N_EDGES = 800000;
static constexpr int DMODEL  = 128;
static constexpr int MTILES  = N_NODES / 16;   // 3125 exactly

typedef __attribute__((ext_vector_type(8))) short short8;   // 8 bf16 (4 VGPRs)
typedef __attribute__((ext_vector_type(4))) float float4v;  // 4 fp32 acc

__device__ __forceinline__ unsigned short f2bf(float f) {
    unsigned u = __builtin_bit_cast(unsigned, f);
    u += 0x7fffu + ((u >> 16) & 1u);
    return (unsigned short)(u >> 16);
}
__device__ __forceinline__ float bflo(unsigned w) {   // low bf16 -> f32 (1 shl)
    return __builtin_bit_cast(float, w << 16);
}
__device__ __forceinline__ float bfhi(unsigned w) {   // high bf16 -> f32 (1 and)
    return __builtin_bit_cast(float, w & 0xffff0000u);
}

// ---------------------------------------------------------------------------
// Weight prep: fp32 [K][N] row-major -> bf16 MFMA B-fragment order.
//   idx = (nt*ksteps + s)*512 + quad*128 + c*8 + j   (nt=n>>4, c=n&15, s=k>>5)
// ---------------------------------------------------------------------------
struct PrepSeg { const float* src; int K; int N; int dstOff; };
struct PrepArgs { PrepSeg seg[13]; };

__global__ void prep_kernel(PrepArgs pa, unsigned short* wf)
{
    PrepSeg sg = pa.seg[blockIdx.y];
    int e = blockIdx.x * 256 + threadIdx.x;
    int total = sg.K * sg.N;
    if (e >= total) return;
    int n = e % sg.N;
    int k = e / sg.N;
    int ks = sg.K >> 5;
    int nt = n >> 4, c = n & 15, s = k >> 5, q = (k >> 3) & 3, jj = k & 7;
    int di = sg.dstOff + (nt * ks + s) * 512 + q * 128 + c * 8 + jj;
    wf[di] = f2bf(sg.src[e]);
}

// ---------------------------------------------------------------------------
// LDS-free MFMA GEMM body, static grid-stride over 16-row m-tiles.
// NOTE (R4 lesson): atomic tile-queue work stealing regressed 2.5x — with
// GX=391, 1564 waves x 2 tiles = 3128 covers 3125 tiles near-perfectly;
// static distribution IS balanced. Keep grid-stride.
// B-frags resident in VGPRs (loaded once per wave). EPI: 0=bias, 1=bias+relu,
// 2=bias+residual, 3=bias+residual+LayerNorm (needs NT*16==128, colBase==0).
// ---------------------------------------------------------------------------
template<int KSTEPS, int NT, int EPI, bool AF32, bool WRF, bool WRB>
__device__ __forceinline__ void gemm_body(
    const void* __restrict__ Ap, const unsigned short* __restrict__ Wfc,
    const float* __restrict__ bias, const float* res,
    float* Cf, unsigned short* Cb,
    const float* __restrict__ lnw, const float* __restrict__ lnb,
    int ldA, int ldC, int mtiles, int colBase)
{
    const int lane = threadIdx.x & 63;
    const int c = lane & 15;
    const int q = lane >> 4;

    short8 bfrag[NT][KSTEPS];
#pragma unroll
    for (int nt = 0; nt < NT; ++nt)
#pragma unroll
        for (int s = 0; s < KSTEPS; ++s)
            bfrag[nt][s] = *(const short8*)(Wfc + (nt * KSTEPS + s) * 512 + lane * 8);

    float bb[NT];
#pragma unroll
    for (int nt = 0; nt < NT; ++nt)
        bb[nt] = bias ? bias[colBase + nt * 16 + c] : 0.f;

    float lw[NT], lb[NT];
    if (EPI == 3) {
#pragma unroll
        for (int nt = 0; nt < NT; ++nt) {
            lw[nt] = lnw[nt * 16 + c];
            lb[nt] = lnb[nt * 16 + c];
        }
    }

    const int wid = blockIdx.x * 4 + (threadIdx.x >> 6);
    const int nw  = gridDim.x * 4;

    for (int mt = wid; mt < mtiles; mt += nw) {
        const int row0 = mt * 16;
        short8 afrag[KSTEPS];
        if (AF32) {
            const float* A32 = (const float*)Ap;
#pragma unroll
            for (int s = 0; s < KSTEPS; ++s) {
                const float4* p = (const float4*)(A32 + (size_t)(row0 + c) * ldA + s * 32 + q * 8);
                float4 x0 = p[0], x1 = p[1];
                short8 a;
                a[0] = (short)f2bf(x0.x); a[1] = (short)f2bf(x0.y);
                a[2] = (short)f2bf(x0.z); a[3] = (short)f2bf(x0.w);
                a[4] = (short)f2bf(x1.x); a[5] = (short)f2bf(x1.y);
                a[6] = (short)f2bf(x1.z); a[7] = (short)f2bf(x1.w);
                afrag[s] = a;
            }
        } else {
            const unsigned short* Ab = (const unsigned short*)Ap;
#pragma unroll
            for (int s = 0; s < KSTEPS; ++s)
                afrag[s] = *(const short8*)(Ab + (size_t)(row0 + c) * ldA + s * 32 + q * 8);
        }

        float4v acc[NT];
#pragma unroll
        for (int nt = 0; nt < NT; ++nt) acc[nt] = (float4v)0.f;
#pragma unroll
        for (int s = 0; s < KSTEPS; ++s)
#pragma unroll
            for (int nt = 0; nt < NT; ++nt)
                acc[nt] = __builtin_amdgcn_mfma_f32_16x16x32_bf16(afrag[s], bfrag[nt][s], acc[nt], 0, 0, 0);

        // epilogue: C row = row0 + q*4 + r, col = colBase + nt*16 + c
#pragma unroll
        for (int nt = 0; nt < NT; ++nt) {
            const int col = colBase + nt * 16 + c;
#pragma unroll
            for (int r = 0; r < 4; ++r) {
                const int grow = row0 + q * 4 + r;
                float v = acc[nt][r] + bb[nt];
                if (EPI == 2 || EPI == 3) v += res[(size_t)grow * ldC + col];
                if (EPI == 1) v = fmaxf(v, 0.f);
                acc[nt][r] = v;
            }
        }

        if (EPI == 3) {
#pragma unroll
            for (int r = 0; r < 4; ++r) {
                float s = 0.f, ss = 0.f;
#pragma unroll
                for (int nt = 0; nt < NT; ++nt) {
                    float v = acc[nt][r];
                    s += v; ss = fmaf(v, v, ss);
                }
#pragma unroll
                for (int o = 1; o < 16; o <<= 1) {
                    s  += __shfl_xor(s, o, 64);
                    ss += __shfl_xor(ss, o, 64);
                }
                float m   = s * (1.0f / 128.0f);
                float var = ss * (1.0f / 128.0f) - m * m;
                float rs  = rsqrtf(var + 1e-5f);
                const int grow = row0 + q * 4 + r;
#pragma unroll
                for (int nt = 0; nt < NT; ++nt) {
                    float v = (acc[nt][r] - m) * rs * lw[nt] + lb[nt];
                    if (WRF) Cf[(size_t)grow * ldC + nt * 16 + c] = v;
                    if (WRB) Cb[(size_t)grow * ldC + nt * 16 + c] = f2bf(v);
                }
            }
        } else {
#pragma unroll
            for (int nt = 0; nt < NT; ++nt) {
                const int col = colBase + nt * 16 + c;
#pragma unroll
                for (int r = 0; r < 4; ++r) {
                    const int grow = row0 + q * 4 + r;
                    if (WRF) Cf[(size_t)grow * ldC + col] = acc[nt][r];
                    if (WRB) Cb[(size_t)grow * ldC + col] = f2bf(acc[nt][r]);
                }
            }
        }
    }
}

template<int KSTEPS, int NT, int EPI, bool AF32, bool WRF, bool WRB>
__global__ __launch_bounds__(256, 2)
void mfma_gemm(const void* __restrict__ Ap, const unsigned short* __restrict__ Wf,
               const float* __restrict__ bias, const float* res,
               float* Cf, unsigned short* Cb,
               const float* __restrict__ lnw, const float* __restrict__ lnb,
               int ldA, int ldC, int mtiles)
{
    const int colBase = blockIdx.y * NT * 16;
    const unsigned short* Wfc = Wf + (size_t)blockIdx.y * NT * KSTEPS * 512;
    gemm_body<KSTEPS, NT, EPI, AF32, WRF, WRB>(
        Ap, Wfc, bias, res, Cf, Cb, lnw, lnb, ldA, ldC, mtiles, colBase);
}

// Q/K/V fused: blockIdx.y in {0,1,2} selects weight block, bias, output.
struct QkvPtrs { const float* bias[3]; unsigned short* out[3]; };

__global__ __launch_bounds__(256, 2)
void qkv_gemm(const unsigned short* __restrict__ A, const unsigned short* __restrict__ WfBase,
              QkvPtrs ptrs, int mtiles)
{
    const int sel = blockIdx.y;
    gemm_body<4, 8, 0, false, false, true>(
        A, WfBase + (size_t)sel * 32768, ptrs.bias[sel], nullptr,
        nullptr, ptrs.out[sel], nullptr, nullptr, 128, 128, mtiles, 0);
}

// ---------------------------------------------------------------------------
// FFN2 + residual + LN2 fused. K=256 (KSTEPS=8), NT=8 -> full 128-col rows.
// B-frags streamed per k-step from L2 (256 resident VGPRs would spill).
// res aliases outF for layer 0 (row owned by one wave: read-then-write, ok).
// ---------------------------------------------------------------------------
__global__ __launch_bounds__(256, 2)
void ffn2_ln_gemm(const unsigned short* __restrict__ A, const unsigned short* __restrict__ Wf,
                  const float* __restrict__ bias, const float* res,
                  float* outF, unsigned short* outB,
                  const float* __restrict__ lnw, const float* __restrict__ lnb,
                  int mtiles)
{
    const int lane = threadIdx.x & 63;
    const int c = lane & 15;
    const int q = lane >> 4;

    float bb[8], lw[8], lb[8];
#pragma unroll
    for (int nt = 0; nt < 8; ++nt) {
        bb[nt] = bias[nt * 16 + c];
        lw[nt] = lnw[nt * 16 + c];
        lb[nt] = lnb[nt * 16 + c];
    }

    const int wid = blockIdx.x * 4 + (threadIdx.x >> 6);
    const int nw  = gridDim.x * 4;

    for (int mt = wid; mt < mtiles; mt += nw) {
        const int row0 = mt * 16;
        short8 afrag[8];
#pragma unroll
        for (int s = 0; s < 8; ++s)
            afrag[s] = *(const short8*)(A + (size_t)(row0 + c) * 256 + s * 32 + q * 8);

        float4v acc[8];
#pragma unroll
        for (int nt = 0; nt < 8; ++nt) acc[nt] = (float4v)0.f;

#pragma unroll
        for (int s = 0; s < 8; ++s) {
            short8 bfr[8];
#pragma unroll
            for (int nt = 0; nt < 8; ++nt)
                bfr[nt] = *(const short8*)(Wf + (size_t)(nt * 8 + s) * 512 + lane * 8);
#pragma unroll
            for (int nt = 0; nt < 8; ++nt)
                acc[nt] = __builtin_amdgcn_mfma_f32_16x16x32_bf16(afrag[s], bfr[nt], acc[nt], 0, 0, 0);
        }

        // bias + residual
#pragma unroll
        for (int nt = 0; nt < 8; ++nt)
#pragma unroll
            for (int r = 0; r < 4; ++r) {
                const int grow = row0 + q * 4 + r;
                acc[nt][r] += bb[nt] + res[(size_t)grow * 128 + nt * 16 + c];
            }

        // row LayerNorm + store
#pragma unroll
        for (int r = 0; r < 4; ++r) {
            float s = 0.f, ss = 0.f;
#pragma unroll
            for (int nt = 0; nt < 8; ++nt) {
                float v = acc[nt][r];
                s += v; ss = fmaf(v, v, ss);
            }
#pragma unroll
            for (int o = 1; o < 16; o <<= 1) {
                s  += __shfl_xor(s, o, 64);
                ss += __shfl_xor(ss, o, 64);
            }
            float m   = s * (1.0f / 128.0f);
            float var = ss * (1.0f / 128.0f) - m * m;
            float rs  = rsqrtf(var + 1e-5f);
            const int grow = row0 + q * 4 + r;
#pragma unroll
            for (int nt = 0; nt < 8; ++nt) {
                float v = (acc[nt][r] - m) * rs * lw[nt] + lb[nt];
                outF[(size_t)grow * 128 + nt * 16 + c] = v;
                if (outB) outB[(size_t)grow * 128 + nt * 16 + c] = f2bf(v);
            }
        }
    }
}

// ---------------------------------------------------------------------------
// CSR build: histogram -> scan -> scatter (offsets become segment ends).
// ---------------------------------------------------------------------------
__global__ void hist_kernel(const int* __restrict__ dst, int* counts, int E)
{
    int e = blockIdx.x * 256 + threadIdx.x;
    if (e < E) atomicAdd(&counts[dst[e]], 1);
}

__global__ __launch_bounds__(1024)
void scan1_kernel(const int* __restrict__ counts, int* offsets, int* blockSums, int N)
{
    __shared__ int sm[1024];
    int t = threadIdx.x;
    int i = blockIdx.x * 1024 + t;
    sm[t] = (i < N) ? counts[i] : 0;
    __syncthreads();
#pragma unroll
    for (int o = 1; o < 1024; o <<= 1) {
        int v = (t >= o) ? sm[t - o] : 0;
        __syncthreads();
        sm[t] += v;
        __syncthreads();
    }
    if (i < N) offsets[i + 1] = sm[t];
    if (t == 1023) blockSums[blockIdx.x] = sm[t];
}

__global__ void scan2_kernel(int* blockSums, int nb)
{
    int t = threadIdx.x;
    int own = (t < nb) ? blockSums[t] : 0;
    int x = own;
#pragma unroll
    for (int o = 1; o < 64; o <<= 1) {
        int v = __shfl_up(x, o, 64);
        if (t >= o) x += v;
    }
    if (t < nb) blockSums[t] = x - own;
}

__global__ __launch_bounds__(1024)
void scan3_kernel(int* offsets, const int* __restrict__ blockSums, int N)
{
    int i = blockIdx.x * 1024 + threadIdx.x;
    if (i < N) offsets[i + 1] += blockSums[blockIdx.x];
    if (i == 0) offsets[0] = 0;
}

__global__ void scatter_kernel(const int* __restrict__ src, const int* __restrict__ dst,
                               int* offsets, int* esrc, int E)
{
    int e = blockIdx.x * 256 + threadIdx.x;
    if (e < E) {
        int d = dst[e];
        int pos = atomicAdd(&offsets[d], 1);
        esrc[pos] = src[e];
    }
}

// ---------------------------------------------------------------------------
// Attention aggregation, 4x unrolled. 32-bit byte offsets off uniform bases
// (saddr-friendly), med3 clamp, single exp2. One wave per dst node.
// attn may alias q (row n read+written only by wave n).
// ---------------------------------------------------------------------------
__global__ __launch_bounds__(256)
void agg_kernel(const unsigned short* qv, const unsigned short* __restrict__ kv,
                const unsigned short* __restrict__ vv, const int* __restrict__ offsets,
                const int* __restrict__ esrc, unsigned short* attn, int n_nodes)
{
    int w    = (int)((blockIdx.x * 256 + threadIdx.x) >> 6);
    int lane = threadIdx.x & 63;
    if (w >= n_nodes) return;
    const unsigned lane4 = (unsigned)lane * 4u;
    const char* kvc = (const char*)kv;
    const char* vvc = (const char*)vv;

    unsigned qb = *(const unsigned*)((const char*)qv + (((unsigned)w << 8) + lane4));
    float qx = bflo(qb), qy = bfhi(qb);
    int beg = (w == 0) ? 0 : offsets[w - 1];
    int end = offsets[w];
    float accx = 0.f, accy = 0.f, z = 0.f;
    const float SCL = 0.36067376022224085f;   // 0.25 * log2(e)

    for (int e = beg; e < end; e += 4) {
        int rem = end - e;
        unsigned o0 = ((unsigned)esrc[e] << 8) + lane4;
        unsigned o1 = ((unsigned)esrc[rem > 1 ? e + 1 : e] << 8) + lane4;
        unsigned o2 = ((unsigned)esrc[rem > 2 ? e + 2 : e] << 8) + lane4;
        unsigned o3 = ((unsigned)esrc[rem > 3 ? e + 3 : e] << 8) + lane4;
        unsigned kb0 = *(const unsigned*)(kvc + o0);
        unsigned kb1 = *(const unsigned*)(kvc + o1);
        unsigned kb2 = *(const unsigned*)(kvc + o2);
        unsigned kb3 = *(const unsigned*)(kvc + o3);
        unsigned vb0 = *(const unsigned*)(vvc + o0);
        unsigned vb1 = *(const unsigned*)(vvc + o1);
        unsigned vb2 = *(const unsigned*)(vvc + o2);
        unsigned vb3 = *(const unsigned*)(vvc + o3);

        float p0 = bflo(kb0) * qx + bfhi(kb0) * qy;
        float p1 = bflo(kb1) * qx + bfhi(kb1) * qy;
        float p2 = bflo(kb2) * qx + bfhi(kb2) * qy;
        float p3 = bflo(kb3) * qx + bfhi(kb3) * qy;
#pragma unroll
        for (int o = 1; o < 8; o <<= 1) {
            p0 += __shfl_xor(p0, o, 8);
            p1 += __shfl_xor(p1, o, 8);
            p2 += __shfl_xor(p2, o, 8);
            p3 += __shfl_xor(p3, o, 8);
        }
        float m1 = (rem > 1) ? 1.f : 0.f;
        float m2 = (rem > 2) ? 1.f : 0.f;
        float m3 = (rem > 3) ? 1.f : 0.f;
        // exp(clip(p*0.25,-5,5)) == exp2(med3(p,-20,20) * 0.25*log2e)
        float sv0 = exp2f(__builtin_amdgcn_fmed3f(p0, -20.f, 20.f) * SCL);
        float sv1 = exp2f(__builtin_amdgcn_fmed3f(p1, -20.f, 20.f) * SCL) * m1;
        float sv2 = exp2f(__builtin_amdgcn_fmed3f(p2, -20.f, 20.f) * SCL) * m2;
        float sv3 = exp2f(__builtin_amdgcn_fmed3f(p3, -20.f, 20.f) * SCL) * m3;

        accx = fmaf(sv0, bflo(vb0), accx);
        accy = fmaf(sv0, bfhi(vb0), accy);
        accx = fmaf(sv1, bflo(vb1), accx);
        accy = fmaf(sv1, bfhi(vb1), accy);
        accx = fmaf(sv2, bflo(vb2), accx);
        accy = fmaf(sv2, bfhi(vb2), accy);
        accx = fmaf(sv3, bflo(vb3), accx);
        accy = fmaf(sv3, bfhi(vb3), accy);
        z += sv0 + sv1 + sv2 + sv3;
    }
    float inv = 1.f / (z + 1e-6f);
    unsigned outw = (unsigned)f2bf(accx * inv) | ((unsigned)f2bf(accy * inv) << 16);
    *(unsigned*)((char*)attn + (((unsigned)w << 8) + lane4)) = outw;
}

// ---------------------------------------------------------------------------
extern "C" void kernel_launch(void* const* d_in, const int* in_sizes, int n_in,
                              void* d_out, int out_size, void* d_ws, size_t ws_size,
                              hipStream_t stream)
{
    const float* h_in  = (const float*)d_in[0];
    const int*   src   = (const int*)d_in[1];
    const int*   dst   = (const int*)d_in[2];
    const float* W_emb = (const float*)d_in[3];
    const float* Wq    = (const float*)d_in[4];
    const float* bq    = (const float*)d_in[5];
    const float* Wk    = (const float*)d_in[6];
    const float* bk    = (const float*)d_in[7];
    const float* Wv    = (const float*)d_in[8];
    const float* bv    = (const float*)d_in[9];
    const float* Wo    = (const float*)d_in[10];
    const float* bo    = (const float*)d_in[11];
    const float* ln1w  = (const float*)d_in[12];
    const float* ln1b  = (const float*)d_in[13];
    const float* Wf1   = (const float*)d_in[14];
    const float* bf1   = (const float*)d_in[15];
    const float* Wf2   = (const float*)d_in[16];
    const float* bf2   = (const float*)d_in[17];
    const float* ln2w  = (const float*)d_in[18];
    const float* ln2b  = (const float*)d_in[19];
    float* out = (float*)d_out;

    const int N = N_NODES, E = N_EDGES;
    const size_t NF = (size_t)N * DMODEL;

    float*          hbuf = (float*)d_ws;
    unsigned short* hbf  = (unsigned short*)(hbuf + NF);
    unsigned short* qbuf = hbf + NF;
    unsigned short* kbuf = qbuf + NF;
    unsigned short* vbuf = kbuf + NF;
    unsigned short* wf   = vbuf + NF;
    int* offsets   = (int*)(wf + 278528);
    int* blockSums = offsets + (N + 1);
    int* counts    = blockSums + 64;
    int* esrc      = counts + N;
    unsigned short* fbuf = kbuf;   // [N][256] bf16 FFN hidden

    const int EMB_O = 0, Q_O = 16384, K_O = 49152, V_O = 81920, O_O = 114688,
              F1_O = 147456, F2_O = 212992;

    const int edgeBlocks = (E + 255) / 256;
    const int scanBlocks = (N + 1023) / 1024;
    const int rowBlocks  = (N + 3) / 4;
    const int GX = 391;   // 1564 waves x 2 tiles = 3128 >= 3125: balanced

    // ---- CSR build ----
    hipMemsetAsync(counts, 0, (size_t)N * sizeof(int), stream);
    hist_kernel<<<edgeBlocks, 256, 0, stream>>>(dst, counts, E);
    scan1_kernel<<<scanBlocks, 1024, 0, stream>>>(counts, offsets, blockSums, N);
    scan2_kernel<<<1, 64, 0, stream>>>(blockSums, scanBlocks);
    scan3_kernel<<<scanBlocks, 1024, 0, stream>>>(offsets, blockSums, N);
    scatter_kernel<<<edgeBlocks, 256, 0, stream>>>(src, dst, offsets, esrc, E);

    // ---- weight prep ----
    PrepArgs pa;
    pa.seg[0]  = {W_emb,          128, 128, EMB_O};
    pa.seg[1]  = {Wq,             128, 128, Q_O};
    pa.seg[2]  = {Wq + 16384,     128, 128, Q_O + 16384};
    pa.seg[3]  = {Wk,             128, 128, K_O};
    pa.seg[4]  = {Wk + 16384,     128, 128, K_O + 16384};
    pa.seg[5]  = {Wv,             128, 128, V_O};
    pa.seg[6]  = {Wv + 16384,     128, 128, V_O + 16384};
    pa.seg[7]  = {Wo,             128, 128, O_O};
    pa.seg[8]  = {Wo + 16384,     128, 128, O_O + 16384};
    pa.seg[9]  = {Wf1,            128, 256, F1_O};
    pa.seg[10] = {Wf1 + 32768,    128, 256, F1_O + 32768};
    pa.seg[11] = {Wf2,            256, 128, F2_O};
    pa.seg[12] = {Wf2 + 32768,    256, 128, F2_O + 32768};
    prep_kernel<<<dim3(128, 13), 256, 0, stream>>>(pa, wf);

    // ---- embedding: h = h_in @ W_emb (fp32 A) -> hbuf + hbf ----
    mfma_gemm<4, 8, 0, true, true, true><<<dim3(GX, 1), 256, 0, stream>>>(
        h_in, wf + EMB_O, nullptr, nullptr, hbuf, hbf, nullptr, nullptr, 128, 128, MTILES);

    for (int l = 0; l < 2; ++l) {
        // Q,K,V in one dispatch
        QkvPtrs qp;
        qp.bias[0] = bq + l * 128; qp.bias[1] = bk + l * 128; qp.bias[2] = bv + l * 128;
        qp.out[0] = qbuf; qp.out[1] = kbuf; qp.out[2] = vbuf;
        qkv_gemm<<<dim3(GX, 3), 256, 0, stream>>>(hbf, wf + Q_O + l * 16384, qp, MTILES);

        // attention aggregate (attn aliases qbuf)
        agg_kernel<<<rowBlocks, 256, 0, stream>>>(qbuf, kbuf, vbuf, offsets, esrc, qbuf, N);

        // hx = LN1(h + attn @ Wo + bo)  [fused GEMM+residual+LN] -> hbuf + hbf
        mfma_gemm<4, 8, 3, false, true, true><<<dim3(GX, 1), 256, 0, stream>>>(
            qbuf, wf + O_O + l * 16384, bo + l * 128, hbuf, hbuf, hbf,
            ln1w + l * 128, ln1b + l * 128, 128, 128, MTILES);

        // f1 = relu(hx @ Wf1 + bf1) -> bf16 [N,256]
        mfma_gemm<4, 8, 1, false, false, true><<<dim3(GX, 2), 256, 0, stream>>>(
            hbf, wf + F1_O + l * 32768, bf1 + l * 256, nullptr, nullptr, fbuf,
            nullptr, nullptr, 128, 256, MTILES);

        // h = LN2(hx + f1 @ Wf2 + bf2)  [fused] -> hbuf+hbf (l0) or out (l1)
        if (l == 0)
            ffn2_ln_gemm<<<dim3(GX, 1), 256, 0, stream>>>(
                fbuf, wf + F2_O, bf2, hbuf, hbuf, hbf, ln2w, ln2b, MTILES);
        else
            ffn2_ln_gemm<<<dim3(GX, 1), 256, 0, stream>>>(
                fbuf, wf + F2_O + 32768, bf2 + 128, hbuf, out, nullptr,
                ln2w + 128, ln2b + 128, MTILES);
    }
}